// Round 2
// baseline (359.145 us; speedup 1.0000x reference)
//
#include <hip/hip_runtime.h>
#include <math.h>

// Problem constants (fixed by the reference).
#define BSZ  2
#define DOPN 32
#define RAN  128   // D (z)
#define AZI  128   // H (y)
#define ELE  32    // W (x)
#define NVOX (RAN * AZI * ELE)   // 524288 voxels per batch
#define VPT  4     // voxels per thread (float4 lanes)
#define TPB  256

__device__ __forceinline__ float sigmoidf_(float t) {
    return 1.0f / (1.0f + __expf(-t));
}

// Kernel A: xyz[b,c,n] = polar->cartesian of coords[b,c,n]. 12.6 MB into d_ws.
// float4 I/O + __sincosf (HW trig) — round 1's libm sincosf cost ~200 us.
__global__ __launch_bounds__(TPB) void xyz_precompute(
    const float* __restrict__ coords, float* __restrict__ xyz)
{
    const int n0 = (blockIdx.x * TPB + threadIdx.x) * VPT;
    const int b  = blockIdx.y;
    const float* cb = coords + (size_t)b * 3 * NVOX;
    const float4 r4 = *(const float4*)(cb + n0);
    const float4 a4 = *(const float4*)(cb + NVOX + n0);
    const float4 e4 = *(const float4*)(cb + 2 * NVOX + n0);
    const float rr[4] = { r4.x, r4.y, r4.z, r4.w };
    const float aa[4] = { a4.x, a4.y, a4.z, a4.w };
    const float ee[4] = { e4.x, e4.y, e4.z, e4.w };
    float X[4], Y[4], Z[4];
    #pragma unroll
    for (int v = 0; v < VPT; ++v) {
        float sa, ca, se, ce;
        __sincosf(aa[v], &sa, &ca);
        __sincosf(ee[v], &se, &ce);
        X[v] = rr[v] * ce * ca;
        Y[v] = rr[v] * ce * sa;
        Z[v] = rr[v] * se;
    }
    float* xb = xyz + (size_t)b * 3 * NVOX;
    *(float4*)(xb + n0)            = make_float4(X[0], X[1], X[2], X[3]);
    *(float4*)(xb + NVOX + n0)     = make_float4(Y[0], Y[1], Y[2], Y[3]);
    *(float4*)(xb + 2 * NVOX + n0) = make_float4(Z[0], Z[1], Z[2], Z[3]);
}

// Kernel B: single-pass online doppler reduction + trilinear warp + loss.
// 4 voxels/thread, all streams loaded as float4.
__global__ __launch_bounds__(TPB) void seg_dop_loss(
    const float* __restrict__ seg, const float* __restrict__ flow,
    const float* __restrict__ x1, const float* __restrict__ dop_arr,
    const float* __restrict__ ori, const float* __restrict__ gumbels,
    const float* __restrict__ xyz, float* __restrict__ out)
{
    __shared__ float s_dop[DOPN];
    __shared__ float s_wave[TPB / 64];

    const int b = blockIdx.y;
    if (threadIdx.x < DOPN) s_dop[threadIdx.x] = dop_arr[b * DOPN + threadIdx.x];
    __syncthreads();

    const int n0 = (blockIdx.x * TPB + threadIdx.x) * VPT;
    const size_t base = (size_t)b * DOPN * NVOX + (size_t)n0;

    // ---- DOP axis, one pass: argmax(x1+gumbels) + unnormalized softmax(x1)·dop ----
    // x1 ~ N(0,1): exp() without max-subtraction is safe in fp32.
    float m_lg[VPT] = { -3.4e38f, -3.4e38f, -3.4e38f, -3.4e38f };
    float ssum[VPT] = { 0.f, 0.f, 0.f, 0.f };
    float wsum[VPT] = { 0.f, 0.f, 0.f, 0.f };
    int   idx[VPT]  = { 0, 0, 0, 0 };

    #pragma unroll 4
    for (int d = 0; d < DOPN; ++d) {
        const float4 xv4 = *(const float4*)(x1      + base + (size_t)d * NVOX);
        const float4 gv4 = *(const float4*)(gumbels + base + (size_t)d * NVOX);
        const float dv = s_dop[d];
        const float xv[4] = { xv4.x, xv4.y, xv4.z, xv4.w };
        const float gv[4] = { gv4.x, gv4.y, gv4.z, gv4.w };
        #pragma unroll
        for (int v = 0; v < VPT; ++v) {
            const float lg = xv[v] + gv[v];          // TAU = 1.0
            if (lg > m_lg[v]) { m_lg[v] = lg; idx[v] = d; }
            const float ev = __expf(xv[v]);
            ssum[v] += ev;
            wsum[v] += ev * dv;
        }
    }

    // ---- gather per-voxel vectors (all float4, planar layouts) ----
    const float* fl = flow + ((size_t)b * NVOX + (size_t)n0) * 3;
    float fbuf[12];
    *(float4*)(fbuf)     = *(const float4*)(fl);
    *(float4*)(fbuf + 4) = *(const float4*)(fl + 4);
    *(float4*)(fbuf + 8) = *(const float4*)(fl + 8);

    const float* xb = xyz + (size_t)b * 3 * NVOX;
    const float4 bX4 = *(const float4*)(xb + n0);
    const float4 bY4 = *(const float4*)(xb + NVOX + n0);
    const float4 bZ4 = *(const float4*)(xb + 2 * NVOX + n0);
    const float bX[4] = { bX4.x, bX4.y, bX4.z, bX4.w };
    const float bY[4] = { bY4.x, bY4.y, bY4.z, bY4.w };
    const float bZ[4] = { bZ4.x, bZ4.y, bZ4.z, bZ4.w };

    const float* ob = ori + (size_t)b * 3 * NVOX;
    const float4 oX4 = *(const float4*)(ob + n0);
    const float4 oY4 = *(const float4*)(ob + NVOX + n0);
    const float4 oZ4 = *(const float4*)(ob + 2 * NVOX + n0);
    const float oX[4] = { oX4.x, oX4.y, oX4.z, oX4.w };
    const float oY[4] = { oY4.x, oY4.y, oY4.z, oY4.w };
    const float oZ[4] = { oZ4.x, oZ4.y, oZ4.z, oZ4.w };

    const float4 sg4 = *(const float4*)(seg + (size_t)b * NVOX + n0);
    const float sg[4] = { sg4.x, sg4.y, sg4.z, sg4.w };

    // y,z shared by the 4 consecutive-x voxels (VPT divides ELE).
    const int xB = n0 & (ELE - 1);
    const int yI = (n0 >> 5) & (AZI - 1);
    const int zI = n0 >> 12;

    float contrib = 0.0f;
    #pragma unroll
    for (int v = 0; v < VPT; ++v) {
        const float vx = (float)(xB + v) + fbuf[3 * v + 0];
        const float vy = (float)yI       + fbuf[3 * v + 1];
        const float vz = (float)zI       + fbuf[3 * v + 2];

        // reference's normalized-grid round trip, then border clamp
        const float gx = 2.0f * vx / (float)(ELE - 1) - 1.0f;
        const float gy = 2.0f * vy / (float)(AZI - 1) - 1.0f;
        const float gz = 2.0f * vz / (float)(RAN - 1) - 1.0f;
        const float ix = fminf(fmaxf((gx + 1.0f) * 0.5f * (float)(ELE - 1), 0.0f), (float)(ELE - 1));
        const float iy = fminf(fmaxf((gy + 1.0f) * 0.5f * (float)(AZI - 1), 0.0f), (float)(AZI - 1));
        const float iz = fminf(fmaxf((gz + 1.0f) * 0.5f * (float)(RAN - 1), 0.0f), (float)(RAN - 1));

        const float x0f = floorf(ix), y0f = floorf(iy), z0f = floorf(iz);
        const float wx = ix - x0f, wy = iy - y0f, wz = iz - z0f;
        int x0 = (int)x0f; x0 = x0 < 0 ? 0 : (x0 > ELE - 1 ? ELE - 1 : x0);
        int y0 = (int)y0f; y0 = y0 < 0 ? 0 : (y0 > AZI - 1 ? AZI - 1 : y0);
        int z0 = (int)z0f; z0 = z0 < 0 ? 0 : (z0 > RAN - 1 ? RAN - 1 : z0);
        const int x1c = x0 + 1 > ELE - 1 ? ELE - 1 : x0 + 1;
        const int y1c = y0 + 1 > AZI - 1 ? AZI - 1 : y0 + 1;
        const int z1c = z0 + 1 > RAN - 1 ? RAN - 1 : z0 + 1;

        const int   zs[2]  = { z0, z1c };
        const int   ys[2]  = { y0, y1c };
        const int   xs[2]  = { x0, x1c };
        const float wzv[2] = { 1.0f - wz, wz };
        const float wyv[2] = { 1.0f - wy, wy };
        const float wxv[2] = { 1.0f - wx, wx };

        float sX = 0.0f, sY = 0.0f, sZ = 0.0f;
        #pragma unroll
        for (int i = 0; i < 2; ++i) {
            #pragma unroll
            for (int j = 0; j < 2; ++j) {
                #pragma unroll
                for (int k = 0; k < 2; ++k) {
                    const float w = wzv[i] * wyv[j] * wxv[k];
                    const int m = (zs[i] * AZI + ys[j]) * ELE + xs[k];
                    sX += w * xb[m];
                    sY += w * xb[NVOX + m];
                    sZ += w * xb[2 * NVOX + m];
                }
            }
        }

        const float vX = (sX - bX[v]) * 10.0f;   // / INTERVAL(0.1)
        const float vY = (sY - bY[v]) * 10.0f;
        const float vZ = (sZ - bZ[v]) * 10.0f;
        const float dop_label = vX * oX[v] + vY * oY[v] + vZ * oZ[v];

        const float dop1 = s_dop[idx[v]];
        const float dop2 = wsum[v] / ssum[v];
        float e1 = dop_label - dop1; e1 *= e1;
        float e2 = dop_label - dop2; e2 *= e2;
        const float seg_label = 0.5f * (sigmoidf_(10.0f * (0.15f - e1)) +
                                        sigmoidf_(10.0f * (0.15f - e2)));
        contrib += fabsf(sigmoidf_(sg[v]) - seg_label);
    }

    // ---- block reduction: wave64 shuffle, then partials in LDS ----
    #pragma unroll
    for (int off = 32; off > 0; off >>= 1)
        contrib += __shfl_down(contrib, off, 64);
    const int lane = threadIdx.x & 63;
    const int wid  = threadIdx.x >> 6;
    if (lane == 0) s_wave[wid] = contrib;
    __syncthreads();
    if (threadIdx.x == 0) {
        float bsum = 0.0f;
        #pragma unroll
        for (int w = 0; w < TPB / 64; ++w) bsum += s_wave[w];
        atomicAdd(out, bsum * (1.0f / ((float)BSZ * (float)NVOX)));
    }
}

extern "C" void kernel_launch(void* const* d_in, const int* in_sizes, int n_in,
                              void* d_out, int out_size, void* d_ws, size_t ws_size,
                              hipStream_t stream) {
    const float* seg    = (const float*)d_in[0];
    const float* flow   = (const float*)d_in[1];
    const float* x1     = (const float*)d_in[2];
    const float* dopar  = (const float*)d_in[3];
    const float* coords = (const float*)d_in[4];
    const float* ori    = (const float*)d_in[5];
    const float* gumb   = (const float*)d_in[6];
    float* out = (float*)d_out;
    float* xyz = (float*)d_ws;   // 3*BSZ*NVOX*4 = 12.6 MB

    hipMemsetAsync(d_out, 0, sizeof(float) * (size_t)out_size, stream);

    dim3 grid(NVOX / (TPB * VPT), BSZ);
    xyz_precompute<<<grid, TPB, 0, stream>>>(coords, xyz);
    seg_dop_loss<<<grid, TPB, 0, stream>>>(seg, flow, x1, dopar, ori, gumb, xyz, out);
}

// Round 3
// 325.250 us; speedup vs baseline: 1.1042x; 1.1042x over previous
//
#include <hip/hip_runtime.h>
#include <math.h>

// Problem constants (fixed by the reference).
#define BSZ  2
#define DOPN 32
#define RAN  128   // D (z)
#define AZI  128   // H (y)
#define ELE  32    // W (x)
#define NVOX (RAN * AZI * ELE)   // 524288 voxels per batch
#define TPB  256
#define VPT  2     // voxels per thread in kernel B
#define DH   16    // DOP half (register-burst size)

__device__ __forceinline__ float sigmoidf_(float t) {
    return 1.0f / (1.0f + __expf(-t));
}

// Kernel A: xyz4[b][n] = {x,y,z,0} cartesian of coords. Interleaved float4 so
// kernel B's 8-corner gather is 8x float4 instead of 24 scalar loads.
__global__ __launch_bounds__(TPB) void xyz_precompute(
    const float* __restrict__ coords, float4* __restrict__ xyz4)
{
    const int n = blockIdx.x * TPB + threadIdx.x;
    const int b = blockIdx.y;
    const float* cb = coords + (size_t)b * 3 * NVOX;
    const float r = cb[n];
    const float a = cb[NVOX + n];
    const float e = cb[2 * NVOX + n];
    float sa, ca, se, ce;
    __sincosf(a, &sa, &ca);
    __sincosf(e, &se, &ce);
    xyz4[(size_t)b * NVOX + n] = make_float4(r * ce * ca, r * ce * sa, r * se, 0.0f);
}

// Kernel B: per-voxel DOP reduction (argmax of x1+gumbels, softmax(x1)·dop)
// + trilinear warp + loss. VPT=2; DOP loads register-burst in halves of 16
// (32 outstanding float2 loads per wave) to break latency serialization.
__global__ __launch_bounds__(TPB) void seg_dop_loss(
    const float* __restrict__ seg, const float* __restrict__ flow,
    const float* __restrict__ x1, const float* __restrict__ dop_arr,
    const float* __restrict__ ori, const float* __restrict__ gumbels,
    const float4* __restrict__ xyz4, float* __restrict__ out)
{
    __shared__ float s_dop[DOPN];
    __shared__ float s_wave[TPB / 64];

    const int b = blockIdx.y;
    if (threadIdx.x < DOPN) s_dop[threadIdx.x] = dop_arr[b * DOPN + threadIdx.x];
    __syncthreads();

    const int n0 = (blockIdx.x * TPB + threadIdx.x) * VPT;
    const size_t base = (size_t)b * DOPN * NVOX + (size_t)n0;

    // ---- DOP axis: argmax(x1+gumbels) + unnormalized softmax(x1)·dop ----
    // x1 ~ N(0,1): exp without max-subtraction is fp32-safe and exact here.
    float m_lg[VPT] = { -3.4e38f, -3.4e38f };
    float ssum[VPT] = { 0.f, 0.f };
    float wsum[VPT] = { 0.f, 0.f };
    int   idx[VPT]  = { 0, 0 };

    for (int h = 0; h < 2; ++h) {                  // runtime loop: regs reused
        const size_t dbase = base + (size_t)h * DH * NVOX;
        float2 xa[DH], ga[DH];
        #pragma unroll
        for (int d = 0; d < DH; ++d)
            xa[d] = *(const float2*)(x1 + dbase + (size_t)d * NVOX);
        #pragma unroll
        for (int d = 0; d < DH; ++d)
            ga[d] = *(const float2*)(gumbels + dbase + (size_t)d * NVOX);
        #pragma unroll
        for (int d = 0; d < DH; ++d) {
            const int dg = h * DH + d;
            const float dv = s_dop[dg];
            const float xv[VPT] = { xa[d].x, xa[d].y };
            const float gv[VPT] = { ga[d].x, ga[d].y };
            #pragma unroll
            for (int v = 0; v < VPT; ++v) {
                const float lg = xv[v] + gv[v];      // TAU = 1.0
                if (lg > m_lg[v]) { m_lg[v] = lg; idx[v] = dg; }
                const float ev = __expf(xv[v]);
                ssum[v] += ev;
                wsum[v] += ev * dv;
            }
        }
    }

    // ---- per-voxel vector loads ----
    const float* fl = flow + ((size_t)b * NVOX + (size_t)n0) * 3;
    float fbuf[3 * VPT];
    *(float2*)(fbuf)     = *(const float2*)(fl);
    *(float2*)(fbuf + 2) = *(const float2*)(fl + 2);
    *(float2*)(fbuf + 4) = *(const float2*)(fl + 4);

    const float4* xb4 = xyz4 + (size_t)b * NVOX;
    float4 bxyz[VPT];
    #pragma unroll
    for (int v = 0; v < VPT; ++v) bxyz[v] = xb4[n0 + v];

    const float* ob = ori + (size_t)b * 3 * NVOX;
    const float2 oX2 = *(const float2*)(ob + n0);
    const float2 oY2 = *(const float2*)(ob + NVOX + n0);
    const float2 oZ2 = *(const float2*)(ob + 2 * NVOX + n0);
    const float oX[VPT] = { oX2.x, oX2.y };
    const float oY[VPT] = { oY2.x, oY2.y };
    const float oZ[VPT] = { oZ2.x, oZ2.y };

    const float2 sg2 = *(const float2*)(seg + (size_t)b * NVOX + n0);
    const float sg[VPT] = { sg2.x, sg2.y };

    // y,z shared by the consecutive-x voxels (VPT divides ELE).
    const int xB = n0 & (ELE - 1);
    const int yI = (n0 >> 5) & (AZI - 1);
    const int zI = n0 >> 12;

    float contrib = 0.0f;
    #pragma unroll
    for (int v = 0; v < VPT; ++v) {
        const float vx = (float)(xB + v) + fbuf[3 * v + 0];
        const float vy = (float)yI       + fbuf[3 * v + 1];
        const float vz = (float)zI       + fbuf[3 * v + 2];

        // reference's normalized-grid round trip, then border clamp
        const float gx = 2.0f * vx / (float)(ELE - 1) - 1.0f;
        const float gy = 2.0f * vy / (float)(AZI - 1) - 1.0f;
        const float gz = 2.0f * vz / (float)(RAN - 1) - 1.0f;
        const float ix = fminf(fmaxf((gx + 1.0f) * 0.5f * (float)(ELE - 1), 0.0f), (float)(ELE - 1));
        const float iy = fminf(fmaxf((gy + 1.0f) * 0.5f * (float)(AZI - 1), 0.0f), (float)(AZI - 1));
        const float iz = fminf(fmaxf((gz + 1.0f) * 0.5f * (float)(RAN - 1), 0.0f), (float)(RAN - 1));

        const float x0f = floorf(ix), y0f = floorf(iy), z0f = floorf(iz);
        const float wx = ix - x0f, wy = iy - y0f, wz = iz - z0f;
        int x0 = (int)x0f; x0 = x0 < 0 ? 0 : (x0 > ELE - 1 ? ELE - 1 : x0);
        int y0 = (int)y0f; y0 = y0 < 0 ? 0 : (y0 > AZI - 1 ? AZI - 1 : y0);
        int z0 = (int)z0f; z0 = z0 < 0 ? 0 : (z0 > RAN - 1 ? RAN - 1 : z0);
        const int x1c = x0 + 1 > ELE - 1 ? ELE - 1 : x0 + 1;
        const int y1c = y0 + 1 > AZI - 1 ? AZI - 1 : y0 + 1;
        const int z1c = z0 + 1 > RAN - 1 ? RAN - 1 : z0 + 1;

        // 8 independent float4 gathers
        const int m00 = (z0  * AZI + y0 ) * ELE;
        const int m01 = (z0  * AZI + y1c) * ELE;
        const int m10 = (z1c * AZI + y0 ) * ELE;
        const int m11 = (z1c * AZI + y1c) * ELE;
        const float4 c000 = xb4[m00 + x0],  c001 = xb4[m00 + x1c];
        const float4 c010 = xb4[m01 + x0],  c011 = xb4[m01 + x1c];
        const float4 c100 = xb4[m10 + x0],  c101 = xb4[m10 + x1c];
        const float4 c110 = xb4[m11 + x0],  c111 = xb4[m11 + x1c];

        const float w000 = (1.0f - wz) * (1.0f - wy) * (1.0f - wx);
        const float w001 = (1.0f - wz) * (1.0f - wy) * wx;
        const float w010 = (1.0f - wz) * wy * (1.0f - wx);
        const float w011 = (1.0f - wz) * wy * wx;
        const float w100 = wz * (1.0f - wy) * (1.0f - wx);
        const float w101 = wz * (1.0f - wy) * wx;
        const float w110 = wz * wy * (1.0f - wx);
        const float w111 = wz * wy * wx;

        const float sX = w000*c000.x + w001*c001.x + w010*c010.x + w011*c011.x
                       + w100*c100.x + w101*c101.x + w110*c110.x + w111*c111.x;
        const float sY = w000*c000.y + w001*c001.y + w010*c010.y + w011*c011.y
                       + w100*c100.y + w101*c101.y + w110*c110.y + w111*c111.y;
        const float sZ = w000*c000.z + w001*c001.z + w010*c010.z + w011*c011.z
                       + w100*c100.z + w101*c101.z + w110*c110.z + w111*c111.z;

        const float vX = (sX - bxyz[v].x) * 10.0f;   // / INTERVAL(0.1)
        const float vY = (sY - bxyz[v].y) * 10.0f;
        const float vZ = (sZ - bxyz[v].z) * 10.0f;
        const float dop_label = vX * oX[v] + vY * oY[v] + vZ * oZ[v];

        const float dop1 = s_dop[idx[v]];
        const float dop2 = wsum[v] / ssum[v];
        float e1 = dop_label - dop1; e1 *= e1;
        float e2 = dop_label - dop2; e2 *= e2;
        const float seg_label = 0.5f * (sigmoidf_(10.0f * (0.15f - e1)) +
                                        sigmoidf_(10.0f * (0.15f - e2)));
        contrib += fabsf(sigmoidf_(sg[v]) - seg_label);
    }

    // ---- block reduction: wave64 shuffle, then partials in LDS ----
    #pragma unroll
    for (int off = 32; off > 0; off >>= 1)
        contrib += __shfl_down(contrib, off, 64);
    const int lane = threadIdx.x & 63;
    const int wid  = threadIdx.x >> 6;
    if (lane == 0) s_wave[wid] = contrib;
    __syncthreads();
    if (threadIdx.x == 0) {
        float bsum = 0.0f;
        #pragma unroll
        for (int w = 0; w < TPB / 64; ++w) bsum += s_wave[w];
        atomicAdd(out, bsum * (1.0f / ((float)BSZ * (float)NVOX)));
    }
}

extern "C" void kernel_launch(void* const* d_in, const int* in_sizes, int n_in,
                              void* d_out, int out_size, void* d_ws, size_t ws_size,
                              hipStream_t stream) {
    const float* seg    = (const float*)d_in[0];
    const float* flow   = (const float*)d_in[1];
    const float* x1     = (const float*)d_in[2];
    const float* dopar  = (const float*)d_in[3];
    const float* coords = (const float*)d_in[4];
    const float* ori    = (const float*)d_in[5];
    const float* gumb   = (const float*)d_in[6];
    float* out = (float*)d_out;
    float4* xyz4 = (float4*)d_ws;   // BSZ*NVOX*16 B = 16.8 MB

    hipMemsetAsync(d_out, 0, sizeof(float) * (size_t)out_size, stream);

    dim3 gridA(NVOX / TPB, BSZ);
    xyz_precompute<<<gridA, TPB, 0, stream>>>(coords, xyz4);
    dim3 gridB(NVOX / (TPB * VPT), BSZ);
    seg_dop_loss<<<gridB, TPB, 0, stream>>>(seg, flow, x1, dopar, ori, gumb, xyz4, out);
}